// Round 4
// baseline (140.344 us; speedup 1.0000x reference)
//
#include <hip/hip_runtime.h>
#include <hip/hip_bf16.h>
#include <stdint.h>

typedef __attribute__((ext_vector_type(8))) short short8;
typedef __attribute__((ext_vector_type(4))) float floatx4;

#define S_LEN 2048
#define DH    128
#define BQ    64
#define BKV   64
#define NSTEP (S_LEN / BKV)
#define SCALE 0.08838834764831845f   // 1/sqrt(128)

__device__ __forceinline__ unsigned short f2b(float f) {
    union { float f; unsigned u; } v; v.f = f;
    unsigned r = v.u + 0x7fffu + ((v.u >> 16) & 1u);
    return (unsigned short)(r >> 16);
}

__device__ __forceinline__ void gll16(const void* g, void* l) {
    __builtin_amdgcn_global_load_lds(
        (__attribute__((address_space(1))) void*)(g),
        (__attribute__((address_space(3))) void*)(l), 16, 0, 0);
}

// ============================ prepass kernels ============================

__global__ __launch_bounds__(256) void conv_k(const float* __restrict__ K,
                                              unsigned short* __restrict__ Kbf)
{
    int i = blockIdx.x * 256 + threadIdx.x;       // one float4 / ushort4
    float4 v = ((const float4*)K)[i];
    ushort4 o;
    o.x = f2b(v.x); o.y = f2b(v.y); o.z = f2b(v.z); o.w = f2b(v.w);
    ((ushort4*)Kbf)[i] = o;
}

__global__ __launch_bounds__(256) void transp_v(const float* __restrict__ V,
                                                unsigned short* __restrict__ Vt)
{
    // grid: (S/32, D/32, B), block 256 = 32x8
    __shared__ float t[32][33];
    const int k0 = blockIdx.x * 32, d0 = blockIdx.y * 32, b = blockIdx.z;
    const int tx = threadIdx.x & 31, ty = threadIdx.x >> 5;  // ty 0..7
    const float* Vb = V + ((size_t)b * S_LEN + k0) * DH + d0;
    #pragma unroll
    for (int i = 0; i < 4; ++i)
        t[ty + 8 * i][tx] = Vb[(size_t)(ty + 8 * i) * DH + tx];
    __syncthreads();
    unsigned short* Vtb = Vt + ((size_t)b * DH + d0) * S_LEN + k0;
    #pragma unroll
    for (int i = 0; i < 4; ++i)
        Vtb[(size_t)(ty + 8 * i) * S_LEN + tx] = f2b(t[tx][ty + 8 * i]);
}

// ============================ main kernel (fast path) ============================
// LDS: KH0 0..16384, KH1 16384..32768 (64 x 256B rows, swizzle via source)
//      VT0 32768..51200, VT1 51200..69632 (128 rows x 144B)
//      PS  69632..77824 (4 waves x 2KB)
#define LDS_BYTES 77824

__global__ __launch_bounds__(256, 2)
void attn_fwd(const float* __restrict__ Q, const unsigned short* __restrict__ Kbf,
              const unsigned short* __restrict__ Vt, const int* __restrict__ M,
              float* __restrict__ O)
{
    __shared__ __align__(128) char lds[LDS_BYTES];

    const int tid  = threadIdx.x;
    const int lane = tid & 63;
    const int w    = tid >> 6;
    const int c    = lane & 15;
    const int g    = lane >> 4;
    const int qt   = blockIdx.x;
    const int b    = blockIdx.y;
    const int q0   = qt * BQ;

    const int vd = tid & 127;          // V^T row (d) owned by this thread
    const int vh = tid >> 7;           // k-half (0/1)

    // ---- Q fragments (scale folded)
    short8 qf[4];
    {
        const float* qrow = Q + ((size_t)(b * S_LEN + q0 + w * 16 + c)) * DH;
        #pragma unroll
        for (int dk = 0; dk < 4; ++dk) {
            const float* p = qrow + dk * 32 + g * 8;
            float4 a  = *(const float4*)(p);
            float4 bb = *(const float4*)(p + 4);
            short8 f;
            f[0] = f2b(a.x * SCALE);  f[1] = f2b(a.y * SCALE);
            f[2] = f2b(a.z * SCALE);  f[3] = f2b(a.w * SCALE);
            f[4] = f2b(bb.x * SCALE); f[5] = f2b(bb.y * SCALE);
            f[6] = f2b(bb.z * SCALE); f[7] = f2b(bb.w * SCALE);
            qf[dk] = f;
        }
    }

    float m_run[4] = {-1e30f, -1e30f, -1e30f, -1e30f};
    float l_run[4] = {0.f, 0.f, 0.f, 0.f};
    floatx4 accO[8];
    #pragma unroll
    for (int i = 0; i < 8; ++i) accO[i] = (floatx4)(0.f);

    const unsigned short* Kb  = Kbf + (size_t)b * S_LEN * DH;   // [k][d] bf16
    const unsigned short* Vtb = Vt  + (size_t)b * DH * S_LEN;   // [d][k] bf16
    const int*            Mb  = M   + (size_t)b * S_LEN * S_LEN + (size_t)q0 * S_LEN;

    size_t moff[4];
    #pragma unroll
    for (int r = 0; r < 4; ++r)
        moff[r] = (size_t)(w * 16 + 4 * g + r) * S_LEN;

    short8 vreg[4];
    int    mreg[16];

    // K tile staging via global_load_lds: 16 x 1KB instrs, wave w does j = 4w+i.
    // lane l covers tile row r = 4j + (l>>4), col bytes (l&15)*16; source col
    // pre-swizzled with ((r&7)<<4) so LDS is linear but logically swizzled.
    const int krow_l = lane >> 4;        // 0..3
    const int kcol_l = (lane & 15) * 16; // 0..240

    // ---- prologue: K tile0 -> KH0
    #pragma unroll
    for (int i = 0; i < 4; ++i) {
        int j = (w << 2) | i;
        int r = j * 4 + krow_l;
        unsigned cb = (unsigned)kcol_l ^ (unsigned)((r & 7) << 4);
        gll16((const char*)Kb + (size_t)r * 256 + cb, lds + j * 1024);
    }
    // V tile0 -> VT0 (reg path, no conversion)
    #pragma unroll
    for (int j = 0; j < 4; ++j)
        vreg[j] = *(const short8*)(Vtb + (size_t)vd * S_LEN + vh * 32 + j * 8);
    #pragma unroll
    for (int j = 0; j < 4; ++j)
        *(short8*)(lds + 32768 + vd * 144 + vh * 64 + j * 16) = vreg[j];
    // mask tile0
    #pragma unroll
    for (int r = 0; r < 4; ++r)
        #pragma unroll
        for (int n = 0; n < 4; ++n)
            mreg[r * 4 + n] = Mb[moff[r] + n * 16 + c];
    // V tile1 -> regs
    #pragma unroll
    for (int j = 0; j < 4; ++j)
        vreg[j] = *(const short8*)(Vtb + (size_t)vd * S_LEN + BKV + vh * 32 + j * 8);

    __syncthreads();

    char* psw = lds + 69632 + w * 2048;

    for (int step = 0; step < NSTEP; ++step) {
        const int p = step & 1;
        const int kv0 = step * BKV;
        char* KHp = lds + p * 16384;
        char* VTp = lds + 32768 + p * 18432;

        // ---- issue K gll for tile step+1 into KH[p^1] (drained by end barrier)
        if (step + 1 < NSTEP) {
            const char* Ksrc = (const char*)Kb + (size_t)(kv0 + BKV) * 256;
            char* KHn = lds + (p ^ 1) * 16384;
            #pragma unroll
            for (int i = 0; i < 4; ++i) {
                int j = (w << 2) | i;
                int r = j * 4 + krow_l;
                unsigned cb = (unsigned)kcol_l ^ (unsigned)((r & 7) << 4);
                gll16(Ksrc + (size_t)r * 256 + cb, KHn + j * 1024);
            }
        }

        // ---- QK^T
        floatx4 accS[4];
        #pragma unroll
        for (int n = 0; n < 4; ++n) accS[n] = (floatx4)(0.f);
        #pragma unroll
        for (int n = 0; n < 4; ++n) {
            const char* krow = KHp + (n * 16 + c) * 256;
            #pragma unroll
            for (int dk = 0; dk < 4; ++dk) {
                unsigned colb = (unsigned)(dk * 64 + g * 16) ^ (unsigned)((c & 7) << 4);
                short8 kf = *(const short8*)(krow + colb);
                accS[n] = __builtin_amdgcn_mfma_f32_16x16x32_bf16(qf[dk], kf, accS[n], 0, 0, 0);
            }
        }

        // ---- online softmax
        float pv[4][4];
        float corr[4];
        #pragma unroll
        for (int r = 0; r < 4; ++r) {
            float sv[4];
            #pragma unroll
            for (int n = 0; n < 4; ++n) {
                float s = accS[n][r];
                if (mreg[r * 4 + n]) s = -1e30f;
                sv[n] = s;
            }
            float tm = fmaxf(fmaxf(sv[0], sv[1]), fmaxf(sv[2], sv[3]));
            #pragma unroll
            for (int off = 1; off < 16; off <<= 1)
                tm = fmaxf(tm, __shfl_xor(tm, off, 64));
            float mn = fmaxf(m_run[r], tm);
            corr[r]  = __expf(m_run[r] - mn);
            m_run[r] = mn;
            float ts = 0.f;
            #pragma unroll
            for (int n = 0; n < 4; ++n) { pv[n][r] = __expf(sv[n] - mn); ts += pv[n][r]; }
            #pragma unroll
            for (int off = 1; off < 16; off <<= 1)
                ts += __shfl_xor(ts, off, 64);
            l_run[r] = l_run[r] * corr[r] + ts;
        }
        // mask prefetch for step+1
        if (step + 1 < NSTEP) {
            const int kvn = kv0 + BKV;
            #pragma unroll
            for (int r = 0; r < 4; ++r)
                #pragma unroll
                for (int n = 0; n < 4; ++n)
                    mreg[r * 4 + n] = Mb[moff[r] + kvn + n * 16 + c];
        }

        #pragma unroll
        for (int s8 = 0; s8 < 8; ++s8) {
            floatx4 o = accO[s8];
            o[0] *= corr[0]; o[1] *= corr[1]; o[2] *= corr[2]; o[3] *= corr[3];
            accO[s8] = o;
        }

        // ---- P -> per-wave LDS (swizzled), same-wave consume
        #pragma unroll
        for (int r = 0; r < 4; ++r) {
            int rl = 4 * g + r;
            #pragma unroll
            for (int n = 0; n < 4; ++n) {
                unsigned colb = (unsigned)((n * 16 + c) * 2) ^ (unsigned)((rl & 7) << 4);
                *(unsigned short*)(psw + rl * 128 + colb) = f2b(pv[n][r]);
            }
        }

        // ---- PV
        #pragma unroll
        for (int sub = 0; sub < 2; ++sub) {
            unsigned colb = (unsigned)(sub * 64 + g * 16) ^ (unsigned)((c & 7) << 4);
            short8 pf = *(const short8*)(psw + c * 128 + colb);
            #pragma unroll
            for (int s8 = 0; s8 < 8; ++s8) {
                short8 vf = *(const short8*)(VTp + (s8 * 16 + c) * 144 + sub * 64 + g * 16);
                accO[s8] = __builtin_amdgcn_mfma_f32_16x16x32_bf16(pf, vf, accO[s8], 0, 0, 0);
            }
        }

        // ---- V: write tile step+1 into VT[p^1]; load tile step+2 into regs
        if (step + 1 < NSTEP) {
            char* VTn = lds + 32768 + (p ^ 1) * 18432;
            #pragma unroll
            for (int j = 0; j < 4; ++j)
                *(short8*)(VTn + vd * 144 + vh * 64 + j * 16) = vreg[j];
            if (step + 2 < NSTEP) {
                const unsigned short* vsrc = Vtb + (size_t)vd * S_LEN + kv0 + 2 * BKV + vh * 32;
                #pragma unroll
                for (int j = 0; j < 4; ++j)
                    vreg[j] = *(const short8*)(vsrc + j * 8);
            }
        }
        __syncthreads();
    }

    // ---- epilogue
    float inv[4];
    #pragma unroll
    for (int r = 0; r < 4; ++r) inv[r] = (l_run[r] > 0.f) ? 1.f / l_run[r] : 0.f;
    float* Ob = O + ((size_t)(b * S_LEN + q0 + w * 16)) * DH;
    #pragma unroll
    for (int s8 = 0; s8 < 8; ++s8) {
        #pragma unroll
        for (int r = 0; r < 4; ++r) {
            Ob[(size_t)(4 * g + r) * DH + s8 * 16 + c] = accO[s8][r] * inv[r];
        }
    }
}

// ============================ fallback (verified round-3 kernel) ============================

__global__ __launch_bounds__(256, 2)
void attn_fwd_fb(const float* __restrict__ Q, const float* __restrict__ K,
                 const float* __restrict__ V, const int* __restrict__ M,
                 float* __restrict__ O)
{
    __shared__ __align__(128) char lds[LDS_BYTES];

    const int tid  = threadIdx.x;
    const int lane = tid & 63;
    const int w    = tid >> 6;
    const int c    = lane & 15;
    const int g    = lane >> 4;
    const int qt   = blockIdx.x;
    const int b    = blockIdx.y;
    const int q0   = qt * BQ;

    const int rbase = tid >> 5;
    const int c4    = tid & 31;
    const unsigned swk = (unsigned)(c4 * 8) ^ (unsigned)(rbase << 4);
    const int vd    = tid & 127;
    const int vk0   = (tid >> 7) * 32;

    short8 qf[4];
    {
        const float* qrow = Q + ((size_t)(b * S_LEN + q0 + w * 16 + c)) * DH;
        #pragma unroll
        for (int dk = 0; dk < 4; ++dk) {
            const float* p = qrow + dk * 32 + g * 8;
            float4 a  = *(const float4*)(p);
            float4 bb = *(const float4*)(p + 4);
            short8 f;
            f[0] = f2b(a.x * SCALE);  f[1] = f2b(a.y * SCALE);
            f[2] = f2b(a.z * SCALE);  f[3] = f2b(a.w * SCALE);
            f[4] = f2b(bb.x * SCALE); f[5] = f2b(bb.y * SCALE);
            f[6] = f2b(bb.z * SCALE); f[7] = f2b(bb.w * SCALE);
            qf[dk] = f;
        }
    }

    float m_run[4] = {-1e30f, -1e30f, -1e30f, -1e30f};
    float l_run[4] = {0.f, 0.f, 0.f, 0.f};
    floatx4 accO[8];
    #pragma unroll
    for (int i = 0; i < 8; ++i) accO[i] = (floatx4)(0.f);

    const float* Kb = K + (size_t)b * S_LEN * DH;
    const float* Vb = V + (size_t)b * S_LEN * DH;
    const int*   Mb = M + (size_t)b * S_LEN * S_LEN + (size_t)q0 * S_LEN;

    size_t moff[4];
    #pragma unroll
    for (int r = 0; r < 4; ++r)
        moff[r] = (size_t)(w * 16 + 4 * g + r) * S_LEN;

    float4 kreg[8];
    float  vreg[32];
    int    mreg[16];

    #pragma unroll
    for (int i = 0; i < 8; ++i)
        kreg[i] = *(const float4*)(Kb + (size_t)(i * 8 + rbase) * DH + c4 * 4);
    #pragma unroll
    for (int j = 0; j < 32; ++j)
        vreg[j] = Vb[(size_t)(vk0 + j) * DH + vd];
    #pragma unroll
    for (int r = 0; r < 4; ++r)
        #pragma unroll
        for (int n = 0; n < 4; ++n)
            mreg[r * 4 + n] = Mb[moff[r] + n * 16 + c];

    #pragma unroll
    for (int i = 0; i < 8; ++i) {
        float4 kv = kreg[i];
        unsigned long long kp =
              (unsigned long long)f2b(kv.x)
            | ((unsigned long long)f2b(kv.y) << 16)
            | ((unsigned long long)f2b(kv.z) << 32)
            | ((unsigned long long)f2b(kv.w) << 48);
        *(unsigned long long*)(lds + (i * 8 + rbase) * 256 + swk) = kp;
    }
    {
        char* vbase = lds + 32768 + vd * 144 + vk0 * 2;
        #pragma unroll
        for (int i = 0; i < 4; ++i) {
            short8 pk;
            #pragma unroll
            for (int e = 0; e < 8; ++e) pk[e] = f2b(vreg[i * 8 + e]);
            *(short8*)(vbase + i * 16) = pk;
        }
    }
    #pragma unroll
    for (int i = 0; i < 8; ++i)
        kreg[i] = *(const float4*)(Kb + (size_t)(BKV + i * 8 + rbase) * DH + c4 * 4);
    #pragma unroll
    for (int j = 0; j < 32; ++j)
        vreg[j] = Vb[(size_t)(BKV + vk0 + j) * DH + vd];

    __syncthreads();

    char* psw = lds + 69632 + w * 2048;

    for (int step = 0; step < NSTEP; ++step) {
        const int p = step & 1;
        const int kv0 = step * BKV;
        char* KHp = lds + p * 16384;
        char* VTp = lds + 32768 + p * 18432;

        floatx4 accS[4];
        #pragma unroll
        for (int n = 0; n < 4; ++n) accS[n] = (floatx4)(0.f);
        #pragma unroll
        for (int n = 0; n < 4; ++n) {
            const char* krow = KHp + (n * 16 + c) * 256;
            #pragma unroll
            for (int dk = 0; dk < 4; ++dk) {
                unsigned colb = (unsigned)(dk * 64 + g * 16) ^ (unsigned)((c & 7) << 4);
                short8 kf = *(const short8*)(krow + colb);
                accS[n] = __builtin_amdgcn_mfma_f32_16x16x32_bf16(qf[dk], kf, accS[n], 0, 0, 0);
            }
        }

        float pv[4][4];
        float corr[4];
        #pragma unroll
        for (int r = 0; r < 4; ++r) {
            float sv[4];
            #pragma unroll
            for (int n = 0; n < 4; ++n) {
                float s = accS[n][r];
                if (mreg[r * 4 + n]) s = -1e30f;
                sv[n] = s;
            }
            float tm = fmaxf(fmaxf(sv[0], sv[1]), fmaxf(sv[2], sv[3]));
            #pragma unroll
            for (int off = 1; off < 16; off <<= 1)
                tm = fmaxf(tm, __shfl_xor(tm, off, 64));
            float mn = fmaxf(m_run[r], tm);
            corr[r]  = __expf(m_run[r] - mn);
            m_run[r] = mn;
            float ts = 0.f;
            #pragma unroll
            for (int n = 0; n < 4; ++n) { pv[n][r] = __expf(sv[n] - mn); ts += pv[n][r]; }
            #pragma unroll
            for (int off = 1; off < 16; off <<= 1)
                ts += __shfl_xor(ts, off, 64);
            l_run[r] = l_run[r] * corr[r] + ts;
        }
        if (step + 1 < NSTEP) {
            const int kvn = kv0 + BKV;
            #pragma unroll
            for (int r = 0; r < 4; ++r)
                #pragma unroll
                for (int n = 0; n < 4; ++n)
                    mreg[r * 4 + n] = Mb[moff[r] + kvn + n * 16 + c];
        }

        #pragma unroll
        for (int s8 = 0; s8 < 8; ++s8) {
            floatx4 o = accO[s8];
            o[0] *= corr[0]; o[1] *= corr[1]; o[2] *= corr[2]; o[3] *= corr[3];
            accO[s8] = o;
        }

        #pragma unroll
        for (int r = 0; r < 4; ++r) {
            int rl = 4 * g + r;
            #pragma unroll
            for (int n = 0; n < 4; ++n) {
                unsigned colb = (unsigned)((n * 16 + c) * 2) ^ (unsigned)((rl & 7) << 4);
                *(unsigned short*)(psw + rl * 128 + colb) = f2b(pv[n][r]);
            }
        }

        #pragma unroll
        for (int sub = 0; sub < 2; ++sub) {
            unsigned colb = (unsigned)(sub * 64 + g * 16) ^ (unsigned)((c & 7) << 4);
            short8 pf = *(const short8*)(psw + c * 128 + colb);
            #pragma unroll
            for (int s8 = 0; s8 < 8; ++s8) {
                short8 vf = *(const short8*)(VTp + (s8 * 16 + c) * 144 + sub * 64 + g * 16);
                accO[s8] = __builtin_amdgcn_mfma_f32_16x16x32_bf16(pf, vf, accO[s8], 0, 0, 0);
            }
        }

        if (step + 1 < NSTEP) {
            char* KHn = lds + (p ^ 1) * 16384;
            char* VTn = lds + 32768 + (p ^ 1) * 18432;
            #pragma unroll
            for (int i = 0; i < 8; ++i) {
                float4 kv = kreg[i];
                unsigned long long kp =
                      (unsigned long long)f2b(kv.x)
                    | ((unsigned long long)f2b(kv.y) << 16)
                    | ((unsigned long long)f2b(kv.z) << 32)
                    | ((unsigned long long)f2b(kv.w) << 48);
                *(unsigned long long*)(KHn + (i * 8 + rbase) * 256 + swk) = kp;
            }
            char* vbase = VTn + vd * 144 + vk0 * 2;
            #pragma unroll
            for (int i = 0; i < 4; ++i) {
                short8 pk;
                #pragma unroll
                for (int e = 0; e < 8; ++e) pk[e] = f2b(vreg[i * 8 + e]);
                *(short8*)(vbase + i * 16) = pk;
            }
            if (step + 2 < NSTEP) {
                const int kvn2 = kv0 + 2 * BKV;
                #pragma unroll
                for (int i = 0; i < 8; ++i)
                    kreg[i] = *(const float4*)(Kb + (size_t)(kvn2 + i * 8 + rbase) * DH + c4 * 4);
                #pragma unroll
                for (int j = 0; j < 32; ++j)
                    vreg[j] = Vb[(size_t)(kvn2 + vk0 + j) * DH + vd];
            }
        }
        __syncthreads();
    }

    float inv[4];
    #pragma unroll
    for (int r = 0; r < 4; ++r) inv[r] = (l_run[r] > 0.f) ? 1.f / l_run[r] : 0.f;
    float* Ob = O + ((size_t)(b * S_LEN + q0 + w * 16)) * DH;
    #pragma unroll
    for (int s8 = 0; s8 < 8; ++s8) {
        #pragma unroll
        for (int r = 0; r < 4; ++r) {
            Ob[(size_t)(4 * g + r) * DH + s8 * 16 + c] = accO[s8][r] * inv[r];
        }
    }
}

extern "C" void kernel_launch(void* const* d_in, const int* in_sizes, int n_in,
                              void* d_out, int out_size, void* d_ws, size_t ws_size,
                              hipStream_t stream) {
    const float* Q = (const float*)d_in[0];
    const float* K = (const float*)d_in[1];
    const float* V = (const float*)d_in[2];
    const int*   M = (const int*)d_in[3];
    float*       O = (float*)d_out;

    const size_t elems = (size_t)16 * S_LEN * DH;          // per tensor
    if (ws_size >= 2 * elems * sizeof(unsigned short)) {
        unsigned short* Kbf = (unsigned short*)d_ws;
        unsigned short* Vt  = (unsigned short*)d_ws + elems;
        conv_k<<<dim3((unsigned)(elems / 4 / 256)), dim3(256), 0, stream>>>(K, Kbf);
        transp_v<<<dim3(S_LEN / 32, DH / 32, 16), dim3(256), 0, stream>>>(V, Vt);
        attn_fwd<<<dim3(S_LEN / BQ, 16), dim3(256), 0, stream>>>(Q, Kbf, Vt, M, O);
    } else {
        attn_fwd_fb<<<dim3(S_LEN / BQ, 16), dim3(256), 0, stream>>>(Q, K, V, M, O);
    }
}

// Round 5
// 121.555 us; speedup vs baseline: 1.1546x; 1.1546x over previous
//
#include <hip/hip_runtime.h>
#include <hip/hip_bf16.h>
#include <stdint.h>

typedef __attribute__((ext_vector_type(8))) short short8;
typedef __attribute__((ext_vector_type(4))) float floatx4;

#define S_LEN 2048
#define DH    128
#define BQ    64
#define BKV   64
#define NSTEP (S_LEN / BKV)
#define SCALE 0.08838834764831845f   // 1/sqrt(128)

__device__ __forceinline__ unsigned short f2b(float f) {
    union { float f; unsigned u; } v; v.f = f;
    unsigned r = v.u + 0x7fffu + ((v.u >> 16) & 1u);
    return (unsigned short)(r >> 16);
}

__device__ __forceinline__ unsigned cvt_pk(float lo, float hi) {
    unsigned r;
    asm("v_cvt_pk_bf16_f32 %0, %1, %2" : "=v"(r) : "v"(lo), "v"(hi));
    return r;
}

__device__ __forceinline__ void gll16(const void* g, void* l) {
    __builtin_amdgcn_global_load_lds(
        (__attribute__((address_space(1))) void*)(g),
        (__attribute__((address_space(3))) void*)(l), 16, 0, 0);
}

// ============================ prepass kernels ============================

__global__ __launch_bounds__(256) void conv_k(const float* __restrict__ K,
                                              unsigned short* __restrict__ Kbf)
{
    int i = blockIdx.x * 256 + threadIdx.x;
    float4 v = ((const float4*)K)[i];
    ushort4 o;
    o.x = f2b(v.x); o.y = f2b(v.y); o.z = f2b(v.z); o.w = f2b(v.w);
    ((ushort4*)Kbf)[i] = o;
}

__global__ __launch_bounds__(256) void transp_v(const float* __restrict__ V,
                                                unsigned short* __restrict__ Vt)
{
    __shared__ float t[32][33];
    const int k0 = blockIdx.x * 32, d0 = blockIdx.y * 32, b = blockIdx.z;
    const int tx = threadIdx.x & 31, ty = threadIdx.x >> 5;
    const float* Vb = V + ((size_t)b * S_LEN + k0) * DH + d0;
    #pragma unroll
    for (int i = 0; i < 4; ++i)
        t[ty + 8 * i][tx] = Vb[(size_t)(ty + 8 * i) * DH + tx];
    __syncthreads();
    unsigned short* Vtb = Vt + ((size_t)b * DH + d0) * S_LEN + k0;
    #pragma unroll
    for (int i = 0; i < 4; ++i)
        Vtb[(size_t)(ty + 8 * i) * S_LEN + tx] = f2b(t[tx][ty + 8 * i]);
}

// ============================ main kernel ============================
// Swapped-operand structure: S^T = mfma(K, Q); O^T = mfma(V^T, P).
// LDS: KH0 0..16384, KH1 16384..32768 (K dbuf, gll w/ source pre-swizzle)
//      VT  32768..51200 (V^T single buf, 128 rows x 144B)
//      PS  51200..59392 (P, 4 waves x 2KB: rows k/4, 8B/q, xor-swizzled)
#define LDS_BYTES 59392

__global__ __launch_bounds__(256, 3)
void attn_fwd(const float* __restrict__ Q, const unsigned short* __restrict__ Kbf,
              const unsigned short* __restrict__ Vt, const int* __restrict__ M,
              float* __restrict__ O)
{
    __shared__ __align__(128) char lds[LDS_BYTES];

    const int tid  = threadIdx.x;
    const int lane = tid & 63;
    const int w    = tid >> 6;
    const int c    = lane & 15;
    const int g    = lane >> 4;
    const int qt   = blockIdx.x;
    const int b    = blockIdx.y;
    const int q0   = qt * BQ;

    const int vd = tid & 127;          // V^T row (d) owned by this thread
    const int vh = tid >> 7;           // k-half (0/1)
    const int krow_l = lane >> 4;      // gll row-within-j
    const int kcol_l = (lane & 15) * 16;

    // ---- Q fragments (scale folded): lane holds Q[q=w*16+c][d=32dk+8g+e]
    short8 qf[4];
    {
        const float* qrow = Q + ((size_t)(b * S_LEN + q0 + w * 16 + c)) * DH;
        #pragma unroll
        for (int dk = 0; dk < 4; ++dk) {
            const float* p = qrow + dk * 32 + g * 8;
            float4 a  = *(const float4*)(p);
            float4 bb = *(const float4*)(p + 4);
            short8 f;
            f[0] = f2b(a.x * SCALE);  f[1] = f2b(a.y * SCALE);
            f[2] = f2b(a.z * SCALE);  f[3] = f2b(a.w * SCALE);
            f[4] = f2b(bb.x * SCALE); f[5] = f2b(bb.y * SCALE);
            f[6] = f2b(bb.z * SCALE); f[7] = f2b(bb.w * SCALE);
            qf[dk] = f;
        }
    }

    float m_run = -1e30f;
    float l_run = 0.f;
    floatx4 accO[8];
    #pragma unroll
    for (int i = 0; i < 8; ++i) accO[i] = (floatx4)(0.f);

    const char*           Kb8 = (const char*)(Kbf + (size_t)b * S_LEN * DH); // 256B rows
    const unsigned short* Vtb = Vt + (size_t)b * DH * S_LEN;                 // [d][k]
    const int* Mrow = M + (size_t)b * S_LEN * S_LEN
                        + (size_t)(q0 + w * 16 + c) * S_LEN + 4 * g;

    short8 vreg[4];
    int4   mregA[4], mregB[4];
    char*  psw = lds + 51200 + w * 2048;

#define LOAD_MASK(DST, TT) {                                                  \
    const int* mp_ = Mrow + (TT) * BKV;                                       \
    DST[0] = *(const int4*)(mp_);                                             \
    DST[1] = *(const int4*)(mp_ + 16);                                        \
    DST[2] = *(const int4*)(mp_ + 32);                                        \
    DST[3] = *(const int4*)(mp_ + 48); }

    // ---- prologue
    #pragma unroll
    for (int i = 0; i < 4; ++i) {                  // K(0) -> KH0 via gll
        int j = (w << 2) | i;
        int r = 4 * j + krow_l;
        unsigned cb = (unsigned)kcol_l ^ (unsigned)((r & 7) << 4);
        gll16(Kb8 + (size_t)r * 256 + cb, lds + j * 1024);
    }
    #pragma unroll
    for (int j = 0; j < 4; ++j)                    // vreg = V(0)
        vreg[j] = *(const short8*)(Vtb + (size_t)vd * S_LEN + vh * 32 + j * 8);
    LOAD_MASK(mregA, 0);
    LOAD_MASK(mregB, 1);
    __syncthreads();                                // drains gll K(0)

#define STEP_BODY(T, MCUR) {                                                  \
    const int pb  = (T) & 1;                                                  \
    const int kv0 = (T) * BKV;                                                \
    /* phase1: gll K(T+1) into other buffer (full-step window) */             \
    if ((T) + 1 < NSTEP) {                                                    \
        const char* Ksrc = Kb8 + (size_t)(kv0 + BKV) * 256;                   \
        char* KHn = lds + ((pb ^ 1) * 16384);                                 \
        _Pragma("unroll")                                                     \
        for (int i = 0; i < 4; ++i) {                                         \
            int j = (w << 2) | i;                                             \
            int r = 4 * j + krow_l;                                           \
            unsigned cb = (unsigned)kcol_l ^ (unsigned)((r & 7) << 4);        \
            gll16(Ksrc + (size_t)r * 256 + cb, KHn + j * 1024);               \
        }                                                                     \
    }                                                                         \
    /* phase2: write VT(T) from vreg */                                       \
    _Pragma("unroll")                                                         \
    for (int j = 0; j < 4; ++j)                                               \
        *(short8*)(lds + 32768 + vd * 144 + vh * 64 + j * 16) = vreg[j];      \
    /* phase3: issue vreg = V(T+1) */                                         \
    if ((T) + 1 < NSTEP) {                                                    \
        const unsigned short* vs_ = Vtb + (size_t)vd * S_LEN                  \
                                   + (kv0 + BKV) + vh * 32;                   \
        _Pragma("unroll")                                                     \
        for (int j = 0; j < 4; ++j)                                           \
            vreg[j] = *(const short8*)(vs_ + j * 8);                          \
    }                                                                         \
    /* phase4: QK^T (S^T): accS[n] = K-rows(16n..) x Q */                     \
    floatx4 accS[4];                                                          \
    _Pragma("unroll")                                                         \
    for (int n = 0; n < 4; ++n) accS[n] = (floatx4)(0.f);                     \
    {                                                                         \
        const char* KHp = lds + pb * 16384;                                   \
        _Pragma("unroll")                                                     \
        for (int n = 0; n < 4; ++n) {                                         \
            const char* krow = KHp + (n * 16 + c) * 256;                      \
            _Pragma("unroll")                                                 \
            for (int dk = 0; dk < 4; ++dk) {                                  \
                short8 kf = *(const short8*)(krow +                           \
                    ((unsigned)(dk * 64 + g * 16) ^ (unsigned)((c & 7) << 4)));\
                accS[n] = __builtin_amdgcn_mfma_f32_16x16x32_bf16(            \
                              kf, qf[dk], accS[n], 0, 0, 0);                  \
            }                                                                 \
        }                                                                     \
    }                                                                         \
    /* phase5: in-lane softmax (q = c is lane-local; k = 16n+4g+r) */         \
    float p_[4][4];                                                           \
    _Pragma("unroll")                                                         \
    for (int n = 0; n < 4; ++n) {                                             \
        int4 mm = MCUR[n];                                                    \
        p_[n][0] = mm.x ? -1e30f : accS[n][0];                                \
        p_[n][1] = mm.y ? -1e30f : accS[n][1];                                \
        p_[n][2] = mm.z ? -1e30f : accS[n][2];                                \
        p_[n][3] = mm.w ? -1e30f : accS[n][3];                                \
    }                                                                         \
    float mx = p_[0][0];                                                      \
    _Pragma("unroll")                                                         \
    for (int n = 0; n < 4; ++n)                                               \
        _Pragma("unroll")                                                     \
        for (int r = 0; r < 4; ++r) mx = fmaxf(mx, p_[n][r]);                 \
    mx = fmaxf(mx, __shfl_xor(mx, 16));                                       \
    mx = fmaxf(mx, __shfl_xor(mx, 32));                                       \
    float mn   = fmaxf(m_run, mx);                                            \
    float corr = __expf(m_run - mn);                                          \
    m_run = mn;                                                               \
    float ts = 0.f;                                                           \
    _Pragma("unroll")                                                         \
    for (int n = 0; n < 4; ++n)                                               \
        _Pragma("unroll")                                                     \
        for (int r = 0; r < 4; ++r) {                                         \
            p_[n][r] = __expf(p_[n][r] - mn);                                 \
            ts += p_[n][r];                                                   \
        }                                                                     \
    ts += __shfl_xor(ts, 16);                                                 \
    ts += __shfl_xor(ts, 32);                                                 \
    l_run = l_run * corr + ts;                                                \
    /* mask prefetch T+2 into MCUR (2-step window) */                         \
    if ((T) + 2 < NSTEP) LOAD_MASK(MCUR, (T) + 2);                            \
    /* P -> per-wave LDS: row k4=4n+g holds k=4*k4..+3, 8B per q */           \
    _Pragma("unroll")                                                         \
    for (int n = 0; n < 4; ++n) {                                             \
        unsigned w0 = cvt_pk(p_[n][0], p_[n][1]);                             \
        unsigned w1 = cvt_pk(p_[n][2], p_[n][3]);                             \
        unsigned long long pk = (unsigned long long)w0                        \
                              | ((unsigned long long)w1 << 32);               \
        *(unsigned long long*)(psw + (4 * n + g) * 128                        \
                               + ((c * 8) ^ (g << 3))) = pk;                  \
    }                                                                         \
    /* phase6: rescale accO by scalar corr */                                 \
    _Pragma("unroll")                                                         \
    for (int s8 = 0; s8 < 8; ++s8) {                                          \
        floatx4 o = accO[s8];                                                 \
        o[0] *= corr; o[1] *= corr; o[2] *= corr; o[3] *= corr;               \
        accO[s8] = o;                                                         \
    }                                                                         \
    /* barrier B: LDS-only (no vmcnt drain) */                                \
    asm volatile("s_waitcnt lgkmcnt(0)" ::: "memory");                        \
    __builtin_amdgcn_s_barrier();                                             \
    /* phase8: PV: O^T += V^T x P */                                          \
    _Pragma("unroll")                                                         \
    for (int sub = 0; sub < 2; ++sub) {                                       \
        int ra = 8 * sub + 2 * g;                                             \
        unsigned long long lo = *(const unsigned long long*)(psw + ra * 128   \
                                + ((c * 8) ^ ((ra & 3) << 3)));               \
        unsigned long long hi = *(const unsigned long long*)(psw + (ra+1)*128 \
                                + ((c * 8) ^ (((ra + 1) & 3) << 3)));         \
        union { unsigned long long q[2]; short8 v; } pu;                      \
        pu.q[0] = lo; pu.q[1] = hi;                                           \
        short8 pf = pu.v;                                                     \
        _Pragma("unroll")                                                     \
        for (int s8 = 0; s8 < 8; ++s8) {                                      \
            short8 vf = *(const short8*)(lds + 32768 + (s8 * 16 + c) * 144    \
                                         + sub * 64 + g * 16);                \
            accO[s8] = __builtin_amdgcn_mfma_f32_16x16x32_bf16(               \
                           vf, pf, accO[s8], 0, 0, 0);                        \
        }                                                                     \
    }                                                                         \
    /* barrier A */                                                           \
    __syncthreads(); }

    for (int t = 0; t < NSTEP; t += 2) {
        STEP_BODY(t,     mregA)
        STEP_BODY(t + 1, mregB)
    }
#undef STEP_BODY
#undef LOAD_MASK

    // ---- epilogue: lane holds O^T[d=16s8+4g+r][q = q0+w*16+c]
    float inv = (l_run > 0.f) ? 1.f / l_run : 0.f;
    float* Ob = O + ((size_t)(b * S_LEN + q0 + w * 16 + c)) * DH;
    #pragma unroll
    for (int s8 = 0; s8 < 8; ++s8) {
        float4 ov;
        ov.x = accO[s8][0] * inv; ov.y = accO[s8][1] * inv;
        ov.z = accO[s8][2] * inv; ov.w = accO[s8][3] * inv;
        *(float4*)(Ob + s8 * 16 + 4 * g) = ov;
    }
}

// ============================ fallback (verified round-3 kernel) ============================
#define FB_LDS_BYTES 77824

__global__ __launch_bounds__(256, 2)
void attn_fwd_fb(const float* __restrict__ Q, const float* __restrict__ K,
                 const float* __restrict__ V, const int* __restrict__ M,
                 float* __restrict__ O)
{
    __shared__ __align__(128) char lds[FB_LDS_BYTES];

    const int tid  = threadIdx.x;
    const int lane = tid & 63;
    const int w    = tid >> 6;
    const int c    = lane & 15;
    const int g    = lane >> 4;
    const int qt   = blockIdx.x;
    const int b    = blockIdx.y;
    const int q0   = qt * BQ;

    const int rbase = tid >> 5;
    const int c4    = tid & 31;
    const unsigned swk = (unsigned)(c4 * 8) ^ (unsigned)(rbase << 4);
    const int vd    = tid & 127;
    const int vk0   = (tid >> 7) * 32;

    short8 qf[4];
    {
        const float* qrow = Q + ((size_t)(b * S_LEN + q0 + w * 16 + c)) * DH;
        #pragma unroll
        for (int dk = 0; dk < 4; ++dk) {
            const float* p = qrow + dk * 32 + g * 8;
            float4 a  = *(const float4*)(p);
            float4 bb = *(const float4*)(p + 4);
            short8 f;
            f[0] = f2b(a.x * SCALE);  f[1] = f2b(a.y * SCALE);
            f[2] = f2b(a.z * SCALE);  f[3] = f2b(a.w * SCALE);
            f[4] = f2b(bb.x * SCALE); f[5] = f2b(bb.y * SCALE);
            f[6] = f2b(bb.z * SCALE); f[7] = f2b(bb.w * SCALE);
            qf[dk] = f;
        }
    }

    float m_run[4] = {-1e30f, -1e30f, -1e30f, -1e30f};
    float l_run[4] = {0.f, 0.f, 0.f, 0.f};
    floatx4 accO[8];
    #pragma unroll
    for (int i = 0; i < 8; ++i) accO[i] = (floatx4)(0.f);

    const float* Kb = K + (size_t)b * S_LEN * DH;
    const float* Vb = V + (size_t)b * S_LEN * DH;
    const int*   Mb = M + (size_t)b * S_LEN * S_LEN + (size_t)q0 * S_LEN;

    size_t moff[4];
    #pragma unroll
    for (int r = 0; r < 4; ++r)
        moff[r] = (size_t)(w * 16 + 4 * g + r) * S_LEN;

    float4 kreg[8];
    float  vreg[32];
    int    mreg[16];

    #pragma unroll
    for (int i = 0; i < 8; ++i)
        kreg[i] = *(const float4*)(Kb + (size_t)(i * 8 + rbase) * DH + c4 * 4);
    #pragma unroll
    for (int j = 0; j < 32; ++j)
        vreg[j] = Vb[(size_t)(vk0 + j) * DH + vd];
    #pragma unroll
    for (int r = 0; r < 4; ++r)
        #pragma unroll
        for (int n = 0; n < 4; ++n)
            mreg[r * 4 + n] = Mb[moff[r] + n * 16 + c];

    #pragma unroll
    for (int i = 0; i < 8; ++i) {
        float4 kv = kreg[i];
        unsigned long long kp =
              (unsigned long long)f2b(kv.x)
            | ((unsigned long long)f2b(kv.y) << 16)
            | ((unsigned long long)f2b(kv.z) << 32)
            | ((unsigned long long)f2b(kv.w) << 48);
        *(unsigned long long*)(lds + (i * 8 + rbase) * 256 + swk) = kp;
    }
    {
        char* vbase = lds + 32768 + vd * 144 + vk0 * 2;
        #pragma unroll
        for (int i = 0; i < 4; ++i) {
            short8 pk;
            #pragma unroll
            for (int e = 0; e < 8; ++e) pk[e] = f2b(vreg[i * 8 + e]);
            *(short8*)(vbase + i * 16) = pk;
        }
    }
    #pragma unroll
    for (int i = 0; i < 8; ++i)
        kreg[i] = *(const float4*)(Kb + (size_t)(BKV + i * 8 + rbase) * DH + c4 * 4);
    #pragma unroll
    for (int j = 0; j < 32; ++j)
        vreg[j] = Vb[(size_t)(BKV + vk0 + j) * DH + vd];

    __syncthreads();

    char* psw = lds + 69632 + w * 2048;

    for (int step = 0; step < NSTEP; ++step) {
        const int p = step & 1;
        const int kv0 = step * BKV;
        char* KHp = lds + p * 16384;
        char* VTp = lds + 32768 + p * 18432;

        floatx4 accS[4];
        #pragma unroll
        for (int n = 0; n < 4; ++n) accS[n] = (floatx4)(0.f);
        #pragma unroll
        for (int n = 0; n < 4; ++n) {
            const char* krow = KHp + (n * 16 + c) * 256;
            #pragma unroll
            for (int dk = 0; dk < 4; ++dk) {
                unsigned colb = (unsigned)(dk * 64 + g * 16) ^ (unsigned)((c & 7) << 4);
                short8 kf = *(const short8*)(krow + colb);
                accS[n] = __builtin_amdgcn_mfma_f32_16x16x32_bf16(qf[dk], kf, accS[n], 0, 0, 0);
            }
        }

        float pv[4][4];
        float corr[4];
        #pragma unroll
        for (int r = 0; r < 4; ++r) {
            float sv[4];
            #pragma unroll
            for (int n = 0; n < 4; ++n) {
                float s = accS[n][r];
                if (mreg[r * 4 + n]) s = -1e30f;
                sv[n] = s;
            }
            float tm = fmaxf(fmaxf(sv[0], sv[1]), fmaxf(sv[2], sv[3]));
            #pragma unroll
            for (int off = 1; off < 16; off <<= 1)
                tm = fmaxf(tm, __shfl_xor(tm, off, 64));
            float mn = fmaxf(m_run[r], tm);
            corr[r]  = __expf(m_run[r] - mn);
            m_run[r] = mn;
            float ts = 0.f;
            #pragma unroll
            for (int n = 0; n < 4; ++n) { pv[n][r] = __expf(sv[n] - mn); ts += pv[n][r]; }
            #pragma unroll
            for (int off = 1; off < 16; off <<= 1)
                ts += __shfl_xor(ts, off, 64);
            l_run[r] = l_run[r] * corr[r] + ts;
        }
        if (step + 1 < NSTEP) {
            const int kvn = kv0 + BKV;
            #pragma unroll
            for (int r = 0; r < 4; ++r)
                #pragma unroll
                for (int n = 0; n < 4; ++n)
                    mreg[r * 4 + n] = Mb[moff[r] + kvn + n * 16 + c];
        }

        #pragma unroll
        for (int s8 = 0; s8 < 8; ++s8) {
            floatx4 o = accO[s8];
            o[0] *= corr[0]; o[1] *= corr[1]; o[2] *= corr[2]; o[3] *= corr[3];
            accO[s8] = o;
        }

        #pragma unroll
        for (int r = 0; r < 4; ++r) {
            int rl = 4 * g + r;
            #pragma unroll
            for (int n = 0; n < 4; ++n) {
                unsigned colb = (unsigned)((n * 16 + c) * 2) ^ (unsigned)((rl & 7) << 4);
                *(unsigned short*)(psw + rl * 128 + colb) = f2b(pv[n][r]);
            }
        }

        #pragma unroll
        for (int sub = 0; sub < 2; ++sub) {
            unsigned colb = (unsigned)(sub * 64 + g * 16) ^ (unsigned)((c & 7) << 4);
            short8 pf = *(const short8*)(psw + c * 128 + colb);
            #pragma unroll
            for (int s8 = 0; s8 < 8; ++s8) {
                short8 vf = *(const short8*)(VTp + (s8 * 16 + c) * 144 + sub * 64 + g * 16);
                accO[s8] = __builtin_amdgcn_mfma_f32_16x16x32_bf16(pf, vf, accO[s8], 0, 0, 0);
            }
        }

        if (step + 1 < NSTEP) {
            char* KHn = lds + (p ^ 1) * 16384;
            char* VTn = lds + 32768 + (p ^ 1) * 18432;
            #pragma unroll
            for (int i = 0; i < 8; ++i) {
                float4 kv = kreg[i];
                unsigned long long kp =
                      (unsigned long long)f2b(kv.x)
                    | ((unsigned long long)f2b(kv.y) << 16)
                    | ((unsigned long long)f2b(kv.z) << 32)
                    | ((unsigned long long)f2b(kv.w) << 48);
                *(unsigned long long*)(KHn + (i * 8 + rbase) * 256 + swk) = kp;
            }
            char* vbase = VTn + vd * 144 + vk0 * 2;
            #pragma unroll
            for (int i = 0; i < 4; ++i) {
                short8 pk;
                #pragma unroll
                for (int e = 0; e < 8; ++e) pk[e] = f2b(vreg[i * 8 + e]);
                *(short8*)(vbase + i * 16) = pk;
            }
            if (step + 2 < NSTEP) {
                const int kvn2 = kv0 + 2 * BKV;
                #pragma unroll
                for (int i = 0; i < 8; ++i)
                    kreg[i] = *(const float4*)(Kb + (size_t)(kvn2 + i * 8 + rbase) * DH + c4 * 4);
                #pragma unroll
                for (int j = 0; j < 32; ++j)
                    vreg[j] = Vb[(size_t)(kvn2 + vk0 + j) * DH + vd];
            }
        }
        __syncthreads();
    }

    float inv[4];
    #pragma unroll
    for (int r = 0; r < 4; ++r) inv[r] = (l_run[r] > 0.f) ? 1.f / l_run[r] : 0.f;
    float* Ob = O + ((size_t)(b * S_LEN + q0 + w * 16)) * DH;
    #pragma unroll
    for (int s8 = 0; s8 < 8; ++s8) {
        #pragma unroll
        for (int r = 0; r < 4; ++r) {
            Ob[(size_t)(4 * g + r) * DH + s8 * 16 + c] = accO[s8][r] * inv[r];
        }
    }
}

extern "C" void kernel_launch(void* const* d_in, const int* in_sizes, int n_in,
                              void* d_out, int out_size, void* d_ws, size_t ws_size,
                              hipStream_t stream) {
    const float* Q = (const float*)d_in[0];
    const float* K = (const float*)d_in[1];
    const float* V = (const float*)d_in[2];
    const int*   M = (const int*)d_in[3];
    float*       O = (float*)d_out;

    const size_t elems = (size_t)16 * S_LEN * DH;
    if (ws_size >= 2 * elems * sizeof(unsigned short)) {
        unsigned short* Kbf = (unsigned short*)d_ws;
        unsigned short* Vt  = (unsigned short*)d_ws + elems;
        conv_k<<<dim3((unsigned)(elems / 4 / 256)), dim3(256), 0, stream>>>(K, Kbf);
        transp_v<<<dim3(S_LEN / 32, DH / 32, 16), dim3(256), 0, stream>>>(V, Vt);
        attn_fwd<<<dim3(S_LEN / BQ, 16), dim3(256), 0, stream>>>(Q, Kbf, Vt, M, O);
    } else {
        attn_fwd_fb<<<dim3(S_LEN / BQ, 16), dim3(256), 0, stream>>>(Q, K, V, M, O);
    }
}

// Round 8
// 115.482 us; speedup vs baseline: 1.2153x; 1.0526x over previous
//
#include <hip/hip_runtime.h>
#include <hip/hip_bf16.h>
#include <stdint.h>

typedef __attribute__((ext_vector_type(8))) short short8;
typedef __attribute__((ext_vector_type(4))) float floatx4;

#define S_LEN 2048
#define DH    128
#define BQ    64
#define BKV   64
#define NSTEP (S_LEN / BKV)
#define SCALE 0.08838834764831845f                  // 1/sqrt(128)
#define SCALE2 0.12753785429791905f                 // SCALE * log2(e)
#define DTHR 11.541560327111708f                    // 8 * log2(e)

__device__ __forceinline__ float ex2(float x) { return __builtin_amdgcn_exp2f(x); }

__device__ __forceinline__ unsigned short f2b(float f) {
    union { float f; unsigned u; } v; v.f = f;
    unsigned r = v.u + 0x7fffu + ((v.u >> 16) & 1u);
    return (unsigned short)(r >> 16);
}

__device__ __forceinline__ unsigned cvt_pk(float lo, float hi) {
    unsigned r;
    asm("v_cvt_pk_bf16_f32 %0, %1, %2" : "=v"(r) : "v"(lo), "v"(hi));
    return r;
}

__device__ __forceinline__ void gll16(const void* g, void* l) {
    __builtin_amdgcn_global_load_lds(
        (__attribute__((address_space(1))) void*)(g),
        (__attribute__((address_space(3))) void*)(l), 16, 0, 0);
}

// ============================ prepass kernels ============================

__global__ __launch_bounds__(256) void conv_k(const float* __restrict__ K,
                                              unsigned short* __restrict__ Kbf)
{
    int i = blockIdx.x * 256 + threadIdx.x;
    float4 v = ((const float4*)K)[i];
    ushort4 o;
    o.x = f2b(v.x); o.y = f2b(v.y); o.z = f2b(v.z); o.w = f2b(v.w);
    ((ushort4*)Kbf)[i] = o;
}

__global__ __launch_bounds__(256) void transp_v(const float* __restrict__ V,
                                                unsigned short* __restrict__ Vt)
{
    __shared__ float t[32][33];
    const int k0 = blockIdx.x * 32, d0 = blockIdx.y * 32, b = blockIdx.z;
    const int tx = threadIdx.x & 31, ty = threadIdx.x >> 5;
    const float* Vb = V + ((size_t)b * S_LEN + k0) * DH + d0;
    #pragma unroll
    for (int i = 0; i < 4; ++i)
        t[ty + 8 * i][tx] = Vb[(size_t)(ty + 8 * i) * DH + tx];
    __syncthreads();
    unsigned short* Vtb = Vt + ((size_t)b * DH + d0) * S_LEN + k0;
    #pragma unroll
    for (int i = 0; i < 4; ++i)
        Vtb[(size_t)(ty + 8 * i) * S_LEN + tx] = f2b(t[tx][ty + 8 * i]);
}

// ============================ main kernel ============================
// Swapped operands: S^T = mfma(K, Q); O^T = mfma(V^T, P).
// One barrier per step. P bounced through per-wave LDS (same-wave, no barrier).
// LDS: KH0 0..16384, KH1 16384..32768 (K dbuf, gll, source pre-swizzle)
//      VT0 32768..51200, VT1 51200..69632 (V^T dbuf, 128 rows x 144B)
//      PS  69632..77824 (4 waves x 2KB: row k>>2, 8B per q, xor-swizzled)
#define LDS_BYTES 77824

__global__ __launch_bounds__(256, 2)
void attn_fwd(const float* __restrict__ Q, const unsigned short* __restrict__ Kbf,
              const unsigned short* __restrict__ Vt, const int* __restrict__ M,
              float* __restrict__ O)
{
    __shared__ __align__(128) char lds[LDS_BYTES];

    const int tid  = threadIdx.x;
    const int lane = tid & 63;
    const int w    = tid >> 6;
    const int c    = lane & 15;
    const int g    = lane >> 4;
    const int qt   = blockIdx.x;
    const int b    = blockIdx.y;
    const int q0   = qt * BQ;

    const int vd = tid & 127;            // V^T row (d) this thread stages
    const int vh = tid >> 7;             // k-half (0/1)
    const int krow_l = lane >> 4;
    const int kcol_l = (lane & 15) * 16;

    // ---- Q fragments (scale*log2e folded)
    short8 qf[4];
    {
        const float* qrow = Q + ((size_t)(b * S_LEN + q0 + w * 16 + c)) * DH;
        #pragma unroll
        for (int dk = 0; dk < 4; ++dk) {
            const float* p = qrow + dk * 32 + g * 8;
            float4 a  = *(const float4*)(p);
            float4 bb = *(const float4*)(p + 4);
            short8 f;
            f[0] = f2b(a.x * SCALE2);  f[1] = f2b(a.y * SCALE2);
            f[2] = f2b(a.z * SCALE2);  f[3] = f2b(a.w * SCALE2);
            f[4] = f2b(bb.x * SCALE2); f[5] = f2b(bb.y * SCALE2);
            f[6] = f2b(bb.z * SCALE2); f[7] = f2b(bb.w * SCALE2);
            qf[dk] = f;
        }
    }

    float m_run = -1e30f;
    float l_run = 0.f;
    floatx4 accO[8];
    #pragma unroll
    for (int i = 0; i < 8; ++i) accO[i] = (floatx4)(0.f);

    const char*           Kb8 = (const char*)(Kbf + (size_t)b * S_LEN * DH);
    const unsigned short* Vtb = Vt + (size_t)b * DH * S_LEN;
    const int* Mrow = M + (size_t)b * S_LEN * S_LEN
                        + (size_t)(q0 + w * 16 + c) * S_LEN + 4 * g;

    short8 vreg[4];
    int4   mregA[4], mregB[4];
    char*  psw = lds + 69632 + w * 2048;

#define LOAD_MASK(DST, TT) {                                                  \
    const int* mp_ = Mrow + (TT) * BKV;                                       \
    DST[0] = *(const int4*)(mp_);                                             \
    DST[1] = *(const int4*)(mp_ + 16);                                        \
    DST[2] = *(const int4*)(mp_ + 32);                                        \
    DST[3] = *(const int4*)(mp_ + 48); }

    // ---- prologue
    #pragma unroll
    for (int i = 0; i < 4; ++i) {                    // K(0) -> KH0
        int j = (w << 2) | i;
        int r = 4 * j + krow_l;
        unsigned cb = (unsigned)kcol_l ^ (unsigned)((r & 7) << 4);
        gll16(Kb8 + (size_t)r * 256 + cb, lds + j * 1024);
    }
    #pragma unroll
    for (int j = 0; j < 4; ++j)                      // V(0) -> regs
        vreg[j] = *(const short8*)(Vtb + (size_t)vd * S_LEN + vh * 32 + j * 8);
    #pragma unroll
    for (int j = 0; j < 4; ++j)                      // -> VT0
        *(short8*)(lds + 32768 + vd * 144 + vh * 64 + j * 16) = vreg[j];
    #pragma unroll
    for (int j = 0; j < 4; ++j)                      // vreg = V(1)
        vreg[j] = *(const short8*)(Vtb + (size_t)vd * S_LEN + BKV + vh * 32 + j * 8);
    LOAD_MASK(mregA, 0);
    LOAD_MASK(mregB, 1);
    __syncthreads();

#define STEP_BODY(T, MCUR) {                                                  \
    const int pb  = (T) & 1;                                                  \
    const int kv0 = (T) * BKV;                                                \
    /* gll K(T+1) -> KH[pb^1] (drained by end-of-step barrier) */             \
    if ((T) + 1 < NSTEP) {                                                    \
        const char* Ksrc = Kb8 + (size_t)(kv0 + BKV) * 256;                   \
        char* KHn = lds + ((pb ^ 1) * 16384);                                 \
        _Pragma("unroll")                                                     \
        for (int i = 0; i < 4; ++i) {                                         \
            int j = (w << 2) | i;                                             \
            int r = 4 * j + krow_l;                                           \
            unsigned cb = (unsigned)kcol_l ^ (unsigned)((r & 7) << 4);        \
            gll16(Ksrc + (size_t)r * 256 + cb, KHn + j * 1024);               \
        }                                                                     \
    }                                                                         \
    /* write VT[pb^1] = V(T+1) from vreg */                                   \
    if ((T) + 1 < NSTEP) {                                                    \
        _Pragma("unroll")                                                     \
        for (int j = 0; j < 4; ++j)                                           \
            *(short8*)(lds + 32768 + (pb ^ 1) * 18432 + vd * 144 + vh * 64    \
                       + j * 16) = vreg[j];                                   \
    }                                                                         \
    /* issue vreg = V(T+2) */                                                 \
    if ((T) + 2 < NSTEP) {                                                    \
        const unsigned short* vs_ = Vtb + (size_t)vd * S_LEN                  \
                                   + (kv0 + 2 * BKV) + vh * 32;               \
        _Pragma("unroll")                                                     \
        for (int j = 0; j < 4; ++j)                                           \
            vreg[j] = *(const short8*)(vs_ + j * 8);                          \
    }                                                                         \
    /* QK^T: lane (c,g) gets S[kv=16n+4g+r][q=c] */                           \
    floatx4 accS[4];                                                          \
    _Pragma("unroll")                                                         \
    for (int n = 0; n < 4; ++n) accS[n] = (floatx4)(0.f);                     \
    {                                                                         \
        const char* KHp = lds + pb * 16384;                                   \
        __builtin_amdgcn_s_setprio(1);                                        \
        _Pragma("unroll")                                                     \
        for (int n = 0; n < 4; ++n) {                                         \
            const char* krow = KHp + (n * 16 + c) * 256;                      \
            _Pragma("unroll")                                                 \
            for (int dk = 0; dk < 4; ++dk) {                                  \
                short8 kf = *(const short8*)(krow +                           \
                    ((unsigned)(dk * 64 + g * 16) ^ (unsigned)((c & 7) << 4)));\
                accS[n] = __builtin_amdgcn_mfma_f32_16x16x32_bf16(            \
                              kf, qf[dk], accS[n], 0, 0, 0);                  \
            }                                                                 \
        }                                                                     \
        __builtin_amdgcn_s_setprio(0);                                        \
    }                                                                         \
    /* in-lane softmax (log2 domain), defer-max */                            \
    float p_[4][4];                                                           \
    _Pragma("unroll")                                                         \
    for (int n = 0; n < 4; ++n) {                                             \
        int4 mm = MCUR[n];                                                    \
        p_[n][0] = mm.x ? -1e30f : accS[n][0];                                \
        p_[n][1] = mm.y ? -1e30f : accS[n][1];                                \
        p_[n][2] = mm.z ? -1e30f : accS[n][2];                                \
        p_[n][3] = mm.w ? -1e30f : accS[n][3];                                \
    }                                                                         \
    float mx = p_[0][0];                                                      \
    _Pragma("unroll")                                                         \
    for (int n = 0; n < 4; ++n)                                               \
        _Pragma("unroll")                                                     \
        for (int r = 0; r < 4; ++r) mx = fmaxf(mx, p_[n][r]);                 \
    mx = fmaxf(mx, __shfl_xor(mx, 16));                                       \
    mx = fmaxf(mx, __shfl_xor(mx, 32));                                       \
    int need = __any(mx - m_run > DTHR);                                      \
    float corr = 1.0f;                                                        \
    if (need) {                                                               \
        float mn = fmaxf(m_run, mx);                                          \
        corr = ex2(m_run - mn);                                               \
        m_run = mn;                                                           \
    }                                                                         \
    float ts = 0.f;                                                           \
    _Pragma("unroll")                                                         \
    for (int n = 0; n < 4; ++n)                                               \
        _Pragma("unroll")                                                     \
        for (int r = 0; r < 4; ++r) {                                         \
            p_[n][r] = ex2(p_[n][r] - m_run);                                 \
            ts += p_[n][r];                                                   \
        }                                                                     \
    ts += __shfl_xor(ts, 16);                                                 \
    ts += __shfl_xor(ts, 32);                                                 \
    if (need) {                                                               \
        l_run = l_run * corr + ts;                                            \
        _Pragma("unroll")                                                     \
        for (int s8 = 0; s8 < 8; ++s8) {                                      \
            floatx4 o = accO[s8];                                             \
            o[0] *= corr; o[1] *= corr; o[2] *= corr; o[3] *= corr;           \
            accO[s8] = o;                                                     \
        }                                                                     \
    } else {                                                                  \
        l_run += ts;                                                          \
    }                                                                         \
    /* mask prefetch T+2 */                                                   \
    if ((T) + 2 < NSTEP) LOAD_MASK(MCUR, (T) + 2);                            \
    /* P -> per-wave LDS bounce (verified R5 pattern): row 4n+g holds         \
       k = 4*(4n+g)+{0..3}, 8B per q column, swizzle (row&3)<<3 */            \
    _Pragma("unroll")                                                         \
    for (int n = 0; n < 4; ++n) {                                             \
        unsigned w0 = cvt_pk(p_[n][0], p_[n][1]);                             \
        unsigned w1 = cvt_pk(p_[n][2], p_[n][3]);                             \
        unsigned long long pk = (unsigned long long)w0                        \
                              | ((unsigned long long)w1 << 32);               \
        *(unsigned long long*)(psw + (4 * n + g) * 128                        \
                               + ((c * 8) ^ (g << 3))) = pk;                  \
    }                                                                         \
    /* PV: read P fragments (same-wave) + MFMA from VT[pb] */                 \
    {                                                                         \
        const char* VTp = lds + 32768 + pb * 18432;                           \
        _Pragma("unroll")                                                     \
        for (int sub = 0; sub < 2; ++sub) {                                   \
            int ra = 8 * sub + 2 * g;                                         \
            unsigned long long lo = *(const unsigned long long*)(psw + ra*128 \
                                    + ((c * 8) ^ ((ra & 3) << 3)));           \
            unsigned long long hi = *(const unsigned long long*)(psw          \
                                    + (ra + 1) * 128                          \
                                    + ((c * 8) ^ (((ra + 1) & 3) << 3)));     \
            union { unsigned long long q[2]; short8 v; } pu;                  \
            pu.q[0] = lo; pu.q[1] = hi;                                       \
            short8 pf = pu.v;                                                 \
            __builtin_amdgcn_s_setprio(1);                                    \
            _Pragma("unroll")                                                 \
            for (int s8 = 0; s8 < 8; ++s8) {                                  \
                short8 vf = *(const short8*)(VTp + (s8 * 16 + c) * 144        \
                                             + sub * 64 + g * 16);            \
                accO[s8] = __builtin_amdgcn_mfma_f32_16x16x32_bf16(           \
                               vf, pf, accO[s8], 0, 0, 0);                    \
            }                                                                 \
            __builtin_amdgcn_s_setprio(0);                                    \
        }                                                                     \
    }                                                                         \
    __syncthreads(); }

    for (int t = 0; t < NSTEP; t += 2) {
        STEP_BODY(t,     mregA)
        STEP_BODY(t + 1, mregB)
    }
#undef STEP_BODY
#undef LOAD_MASK

    // ---- epilogue: lane holds O^T[d = 16*s8 + 4g + r][q = q0 + 16w + c]
    float inv = (l_run > 0.f) ? 1.f / l_run : 0.f;
    float* Ob = O + ((size_t)(b * S_LEN + q0 + w * 16 + c)) * DH;
    #pragma unroll
    for (int s8 = 0; s8 < 8; ++s8) {
        float4 ov;
        ov.x = accO[s8][0] * inv; ov.y = accO[s8][1] * inv;
        ov.z = accO[s8][2] * inv; ov.w = accO[s8][3] * inv;
        *(float4*)(Ob + s8 * 16 + 4 * g) = ov;
    }
}

// ============================ fallback (verified round-3 kernel) ============================
#define FB_LDS_BYTES 77824

__global__ __launch_bounds__(256, 2)
void attn_fwd_fb(const float* __restrict__ Q, const float* __restrict__ K,
                 const float* __restrict__ V, const int* __restrict__ M,
                 float* __restrict__ O)
{
    __shared__ __align__(128) char lds[FB_LDS_BYTES];

    const int tid  = threadIdx.x;
    const int lane = tid & 63;
    const int w    = tid >> 6;
    const int c    = lane & 15;
    const int g    = lane >> 4;
    const int qt   = blockIdx.x;
    const int b    = blockIdx.y;
    const int q0   = qt * BQ;

    const int rbase = tid >> 5;
    const int c4    = tid & 31;
    const unsigned swk = (unsigned)(c4 * 8) ^ (unsigned)(rbase << 4);
    const int vd    = tid & 127;
    const int vk0   = (tid >> 7) * 32;

    short8 qf[4];
    {
        const float* qrow = Q + ((size_t)(b * S_LEN + q0 + w * 16 + c)) * DH;
        #pragma unroll
        for (int dk = 0; dk < 4; ++dk) {
            const float* p = qrow + dk * 32 + g * 8;
            float4 a  = *(const float4*)(p);
            float4 bb = *(const float4*)(p + 4);
            short8 f;
            f[0] = f2b(a.x * SCALE);  f[1] = f2b(a.y * SCALE);
            f[2] = f2b(a.z * SCALE);  f[3] = f2b(a.w * SCALE);
            f[4] = f2b(bb.x * SCALE); f[5] = f2b(bb.y * SCALE);
            f[6] = f2b(bb.z * SCALE); f[7] = f2b(bb.w * SCALE);
            qf[dk] = f;
        }
    }

    float m_run[4] = {-1e30f, -1e30f, -1e30f, -1e30f};
    float l_run[4] = {0.f, 0.f, 0.f, 0.f};
    floatx4 accO[8];
    #pragma unroll
    for (int i = 0; i < 8; ++i) accO[i] = (floatx4)(0.f);

    const float* Kb = K + (size_t)b * S_LEN * DH;
    const float* Vb = V + (size_t)b * S_LEN * DH;
    const int*   Mb = M + (size_t)b * S_LEN * S_LEN + (size_t)q0 * S_LEN;

    size_t moff[4];
    #pragma unroll
    for (int r = 0; r < 4; ++r)
        moff[r] = (size_t)(w * 16 + 4 * g + r) * S_LEN;

    float4 kreg[8];
    float  vreg[32];
    int    mreg[16];

    #pragma unroll
    for (int i = 0; i < 8; ++i)
        kreg[i] = *(const float4*)(Kb + (size_t)(i * 8 + rbase) * DH + c4 * 4);
    #pragma unroll
    for (int j = 0; j < 32; ++j)
        vreg[j] = Vb[(size_t)(vk0 + j) * DH + vd];
    #pragma unroll
    for (int r = 0; r < 4; ++r)
        #pragma unroll
        for (int n = 0; n < 4; ++n)
            mreg[r * 4 + n] = Mb[moff[r] + n * 16 + c];

    #pragma unroll
    for (int i = 0; i < 8; ++i) {
        float4 kv = kreg[i];
        unsigned long long kp =
              (unsigned long long)f2b(kv.x)
            | ((unsigned long long)f2b(kv.y) << 16)
            | ((unsigned long long)f2b(kv.z) << 32)
            | ((unsigned long long)f2b(kv.w) << 48);
        *(unsigned long long*)(lds + (i * 8 + rbase) * 256 + swk) = kp;
    }
    {
        char* vbase = lds + 32768 + vd * 144 + vk0 * 2;
        #pragma unroll
        for (int i = 0; i < 4; ++i) {
            short8 pk;
            #pragma unroll
            for (int e = 0; e < 8; ++e) pk[e] = f2b(vreg[i * 8 + e]);
            *(short8*)(vbase + i * 16) = pk;
        }
    }
    #pragma unroll
    for (int i = 0; i < 8; ++i)
        kreg[i] = *(const float4*)(Kb + (size_t)(BKV + i * 8 + rbase) * DH + c4 * 4);
    #pragma unroll
    for (int j = 0; j < 32; ++j)
        vreg[j] = Vb[(size_t)(BKV + vk0 + j) * DH + vd];

    __syncthreads();

    char* psw = lds + 69632 + w * 2048;

    for (int step = 0; step < NSTEP; ++step) {
        const int p = step & 1;
        const int kv0 = step * BKV;
        char* KHp = lds + p * 16384;
        char* VTp = lds + 32768 + p * 18432;

        floatx4 accS[4];
        #pragma unroll
        for (int n = 0; n < 4; ++n) accS[n] = (floatx4)(0.f);
        #pragma unroll
        for (int n = 0; n < 4; ++n) {
            const char* krow = KHp + (n * 16 + c) * 256;
            #pragma unroll
            for (int dk = 0; dk < 4; ++dk) {
                unsigned colb = (unsigned)(dk * 64 + g * 16) ^ (unsigned)((c & 7) << 4);
                short8 kf = *(const short8*)(krow + colb);
                accS[n] = __builtin_amdgcn_mfma_f32_16x16x32_bf16(qf[dk], kf, accS[n], 0, 0, 0);
            }
        }

        float pv[4][4];
        float corr[4];
        #pragma unroll
        for (int r = 0; r < 4; ++r) {
            float sv[4];
            #pragma unroll
            for (int n = 0; n < 4; ++n) {
                float s = accS[n][r];
                if (mreg[r * 4 + n]) s = -1e30f;
                sv[n] = s;
            }
            float tm = fmaxf(fmaxf(sv[0], sv[1]), fmaxf(sv[2], sv[3]));
            #pragma unroll
            for (int off = 1; off < 16; off <<= 1)
                tm = fmaxf(tm, __shfl_xor(tm, off, 64));
            float mn = fmaxf(m_run[r], tm);
            corr[r]  = __expf(m_run[r] - mn);
            m_run[r] = mn;
            float ts = 0.f;
            #pragma unroll
            for (int n = 0; n < 4; ++n) { pv[n][r] = __expf(sv[n] - mn); ts += pv[n][r]; }
            #pragma unroll
            for (int off = 1; off < 16; off <<= 1)
                ts += __shfl_xor(ts, off, 64);
            l_run[r] = l_run[r] * corr[r] + ts;
        }
        if (step + 1 < NSTEP) {
            const int kvn = kv0 + BKV;
            #pragma unroll
            for (int r = 0; r < 4; ++r)
                #pragma unroll
                for (int n = 0; n < 4; ++n)
                    mreg[r * 4 + n] = Mb[moff[r] + kvn + n * 16 + c];
        }

        #pragma unroll
        for (int s8 = 0; s8 < 8; ++s8) {
            floatx4 o = accO[s8];
            o[0] *= corr[0]; o[1] *= corr[1]; o[2] *= corr[2]; o[3] *= corr[3];
            accO[s8] = o;
        }

        #pragma unroll
        for (int r = 0; r < 4; ++r) {
            int rl = 4 * g + r;
            #pragma unroll
            for (int n = 0; n < 4; ++n) {
                unsigned colb = (unsigned)((n * 16 + c) * 2) ^ (unsigned)((rl & 7) << 4);
                *(unsigned short*)(psw + rl * 128 + colb) = f2b(pv[n][r]);
            }
        }

        #pragma unroll
        for (int sub = 0; sub < 2; ++sub) {
            unsigned colb = (unsigned)(sub * 64 + g * 16) ^ (unsigned)((c & 7) << 4);
            short8 pf = *(const short8*)(psw + c * 128 + colb);
            #pragma unroll
            for (int s8 = 0; s8 < 8; ++s8) {
                short8 vf = *(const short8*)(VTp + (s8 * 16 + c) * 144 + sub * 64 + g * 16);
                accO[s8] = __builtin_amdgcn_mfma_f32_16x16x32_bf16(pf, vf, accO[s8], 0, 0, 0);
            }
        }

        if (step + 1 < NSTEP) {
            char* KHn = lds + (p ^ 1) * 16384;
            char* VTn = lds + 32768 + (p ^ 1) * 18432;
            #pragma unroll
            for (int i = 0; i < 8; ++i) {
                float4 kv = kreg[i];
                unsigned long long kp =
                      (unsigned long long)f2b(kv.x)
                    | ((unsigned long long)f2b(kv.y) << 16)
                    | ((unsigned long long)f2b(kv.z) << 32)
                    | ((unsigned long long)f2b(kv.w) << 48);
                *(unsigned long long*)(KHn + (i * 8 + rbase) * 256 + swk) = kp;
            }
            char* vbase = VTn + vd * 144 + vk0 * 2;
            #pragma unroll
            for (int i = 0; i < 4; ++i) {
                short8 pk;
                #pragma unroll
                for (int e = 0; e < 8; ++e) pk[e] = f2b(vreg[i * 8 + e]);
                *(short8*)(vbase + i * 16) = pk;
            }
            if (step + 2 < NSTEP) {
                const int kvn2 = kv0 + 2 * BKV;
                #pragma unroll
                for (int i = 0; i < 8; ++i)
                    kreg[i] = *(const float4*)(Kb + (size_t)(kvn2 + i * 8 + rbase) * DH + c4 * 4);
                #pragma unroll
                for (int j = 0; j < 32; ++j)
                    vreg[j] = Vb[(size_t)(kvn2 + vk0 + j) * DH + vd];
            }
        }
        __syncthreads();
    }

    float inv[4];
    #pragma unroll
    for (int r = 0; r < 4; ++r) inv[r] = (l_run[r] > 0.f) ? 1.f / l_run[r] : 0.f;
    float* Ob = O + ((size_t)(b * S_LEN + q0 + w * 16)) * DH;
    #pragma unroll
    for (int s8 = 0; s8 < 8; ++s8) {
        #pragma unroll
        for (int r = 0; r < 4; ++r) {
            Ob[(size_t)(4 * g + r) * DH + s8 * 16 + c] = accO[s8][r] * inv[r];
        }
    }
}

extern "C" void kernel_launch(void* const* d_in, const int* in_sizes, int n_in,
                              void* d_out, int out_size, void* d_ws, size_t ws_size,
                              hipStream_t stream) {
    const float* Q = (const float*)d_in[0];
    const float* K = (const float*)d_in[1];
    const float* V = (const float*)d_in[2];
    const int*   M = (const int*)d_in[3];
    float*       O = (float*)d_out;

    const size_t elems = (size_t)16 * S_LEN * DH;
    if (ws_size >= 2 * elems * sizeof(unsigned short)) {
        unsigned short* Kbf = (unsigned short*)d_ws;
        unsigned short* Vt  = (unsigned short*)d_ws + elems;
        conv_k<<<dim3((unsigned)(elems / 4 / 256)), dim3(256), 0, stream>>>(K, Kbf);
        transp_v<<<dim3(S_LEN / 32, DH / 32, 16), dim3(256), 0, stream>>>(V, Vt);
        attn_fwd<<<dim3(S_LEN / BQ, 16), dim3(256), 0, stream>>>(Q, Kbf, Vt, M, O);
    } else {
        attn_fwd_fb<<<dim3(S_LEN / BQ, 16), dim3(256), 0, stream>>>(Q, K, V, M, O);
    }
}